// Round 7
// baseline (790.064 us; speedup 1.0000x reference)
//
#include <hip/hip_runtime.h>

#define NE 32
#define NG 8
#define NK 4
#define ND 2048
#define NH 1024
#define NHS 4096
#define CAPE 1024
#define NT 4096

typedef float f32x4 __attribute__((ext_vector_type(4)));
typedef short s16x8 __attribute__((ext_vector_type(8)));

__device__ __forceinline__ short f2bf(float f) {
    return __builtin_bit_cast(short, (__bf16)f);
}
__device__ __forceinline__ float bf2f(short h) {
    return __builtin_bit_cast(float, ((unsigned)(unsigned short)h) << 16);
}

__device__ __forceinline__ void gload_lds16(const void* g, void* l) {
    __builtin_amdgcn_global_load_lds(
        (const __attribute__((address_space(1))) void*)g,
        (__attribute__((address_space(3))) void*)l, 16, 0, 0);
}

// ---------------------------------------------------------------------------
// Kernel 1: gating. One wave per token. fp32 logits, sigmoid, grouped top-k.
// ---------------------------------------------------------------------------
__global__ __launch_bounds__(256) void gate_kernel(
    const float* __restrict__ X, const float* __restrict__ Gw,
    const float* __restrict__ bias,
    int* __restrict__ topk_idx, float* __restrict__ topk_w)
{
    const int lane = threadIdx.x & 63;
    const int t = blockIdx.x * 4 + (threadIdx.x >> 6);
    const float* x = X + (size_t)t * ND;

    float xr[32];
#pragma unroll
    for (int i = 0; i < 32; i++) xr[i] = x[lane + i * 64];

    float scores[32];
#pragma unroll
    for (int e = 0; e < 32; e++) {
        const float* w = Gw + (size_t)e * ND;
        float a = 0.f;
#pragma unroll
        for (int i = 0; i < 32; i++) a = fmaf(xr[i], w[lane + i * 64], a);
#pragma unroll
        for (int s = 32; s > 0; s >>= 1) a += __shfl_xor(a, s);
        scores[e] = 1.0f / (1.0f + expf(-a));
    }

    float sc_c[32];
#pragma unroll
    for (int e = 0; e < 32; e++) sc_c[e] = scores[e] + bias[e];

    float gs[8];
#pragma unroll
    for (int g = 0; g < 8; g++) {
        float a = sc_c[4 * g], b = sc_c[4 * g + 1], c = sc_c[4 * g + 2], d = sc_c[4 * g + 3];
        float hi1 = fmaxf(a, b), lo1 = fminf(a, b);
        float hi2 = fmaxf(c, d), lo2 = fminf(c, d);
        float m1 = fmaxf(hi1, hi2);
        float m2 = fmaxf(fminf(hi1, hi2), fmaxf(lo1, lo2));
        gs[g] = m1 + m2;
    }

    unsigned gsel = 0;
#pragma unroll
    for (int it = 0; it < 4; it++) {
        int best = -1; float bv = -1e30f;
#pragma unroll
        for (int g = 0; g < 8; g++) {
            bool avail = !((gsel >> g) & 1);
            if (avail && gs[g] > bv) { bv = gs[g]; best = g; }
        }
        gsel |= 1u << best;
    }

    unsigned esel = 0;
    int idxs[4]; float wts[4];
#pragma unroll
    for (int it = 0; it < 4; it++) {
        int best = -1; float bv = -1e30f, braw = 0.f;
#pragma unroll
        for (int e = 0; e < 32; e++) {
            float mv = ((gsel >> (e >> 2)) & 1) ? sc_c[e] : 0.0f;
            bool avail = !((esel >> e) & 1);
            if (avail && mv > bv) { bv = mv; best = e; braw = scores[e]; }
        }
        esel |= 1u << best;
        idxs[it] = best; wts[it] = braw;
    }

    float s = wts[0] + wts[1] + wts[2] + wts[3] + 1e-20f;
    if (lane == 0) {
#pragma unroll
        for (int k = 0; k < 4; k++) {
            topk_idx[t * 4 + k] = idxs[k];
            topk_w[t * 4 + k] = wts[k] / s * 2.5f;
        }
    }
}

// ---------------------------------------------------------------------------
__global__ void zero_cnt(int* cnt) {
    if (threadIdx.x < NE) cnt[threadIdx.x] = 0;
}

__global__ void dispatch_kernel(const int* __restrict__ topk_idx,
                                int* __restrict__ cnt,
                                int* __restrict__ tok_list,
                                int* __restrict__ pos_list)
{
    int i = blockIdx.x * 256 + threadIdx.x;
    int e = topk_idx[i];
    int t = i >> 2;
    int pos = atomicAdd(&cnt[e], 1);
    pos_list[i] = pos;
    if (pos < CAPE) {
        tok_list[e * CAPE + pos] = t;
    }
}

// ---------------------------------------------------------------------------
// f32 -> bf16 bulk conversion (8 elems / thread / iter, grid-stride)
// ---------------------------------------------------------------------------
__global__ __launch_bounds__(256) void cvt_f2bf(const float* __restrict__ in,
                                                short* __restrict__ out, int n8)
{
    int i = blockIdx.x * 256 + threadIdx.x;
    int stride = gridDim.x * 256;
    for (; i < n8; i += stride) {
        const f32x4* p = (const f32x4*)(in + (size_t)i * 8);
        f32x4 a = p[0], b = p[1];
        s16x8 h;
        h[0] = f2bf(a[0]); h[1] = f2bf(a[1]); h[2] = f2bf(a[2]); h[3] = f2bf(a[3]);
        h[4] = f2bf(b[0]); h[5] = f2bf(b[1]); h[6] = f2bf(b[2]); h[7] = f2bf(b[3]);
        *(s16x8*)(out + (size_t)i * 8) = h;
    }
}

// ---------------------------------------------------------------------------
// Combine: out[t] = shared_down[t] (already in out) + sum_k w_k * Ybuf[e_k,pos_k]
// ---------------------------------------------------------------------------
__global__ __launch_bounds__(256) void combine_kernel(
    const int* __restrict__ topk_idx, const float* __restrict__ topk_w,
    const int* __restrict__ pos_list,
    const short* __restrict__ Ybuf, float* __restrict__ out)
{
    const int t = blockIdx.x;
    const int d0 = threadIdx.x * 8;

    int e[NK], p[NK]; float w[NK];
#pragma unroll
    for (int k = 0; k < NK; k++) {
        e[k] = topk_idx[t * NK + k];
        p[k] = pos_list[t * NK + k];
        w[k] = topk_w[t * NK + k];
    }

    float* orow = out + (size_t)t * ND + d0;
    f32x4 o0 = *(f32x4*)(orow);
    f32x4 o1 = *(f32x4*)(orow + 4);

#pragma unroll
    for (int k = 0; k < NK; k++) {
        if (p[k] < CAPE) {
            s16x8 y = *(const s16x8*)(Ybuf + ((size_t)e[k] * CAPE + p[k]) * ND + d0);
            o0[0] = fmaf(w[k], bf2f(y[0]), o0[0]);
            o0[1] = fmaf(w[k], bf2f(y[1]), o0[1]);
            o0[2] = fmaf(w[k], bf2f(y[2]), o0[2]);
            o0[3] = fmaf(w[k], bf2f(y[3]), o0[3]);
            o1[0] = fmaf(w[k], bf2f(y[4]), o1[0]);
            o1[1] = fmaf(w[k], bf2f(y[5]), o1[1]);
            o1[2] = fmaf(w[k], bf2f(y[6]), o1[2]);
            o1[3] = fmaf(w[k], bf2f(y[7]), o1[3]);
        }
    }
    *(f32x4*)(orow) = o0;
    *(f32x4*)(orow + 4) = o1;
}

// ---------------------------------------------------------------------------
// 8-wave GEMM, parameterized tile: BM x BN, BK=64, waves 2M x 4N
// (wave tile (BM/2) x (BN/4)), LDS double-buffer, counted vmcnt across raw
// barriers, setprio around MFMA clusters, both-sides XOR swizzle.
// MODE 0: routed up   (A = Xbf gathered,  B = up_bf[e],  out = relu2 -> Hbuf)
// MODE 1: routed down (A = Hbuf[e],       B = dn_bf[e],  out = Ybuf bf16)
// MODE 2: shared up   (A = Xbf,           B = sup_bf,    out = relu2 -> Sbuf)
// MODE 3: shared down (A = Sbuf,          B = sdn_bf,    out = f32 write)
// ---------------------------------------------------------------------------
template <int MODE, int BM, int BN>
__global__ __launch_bounds__(512, 2) void moe_gemm8(
    const short* __restrict__ Abase, const short* __restrict__ Bbase,
    const int* __restrict__ cnt, const int* __restrict__ tok_list,
    short* __restrict__ Hout, float* __restrict__ out)
{
    constexpr int K = (MODE == 0) ? ND : (MODE == 1) ? NH : (MODE == 2) ? ND : NHS;
    constexpr int NTILES = K / 64;
    constexpr int MF = BM / 32;            // A-frags per wave (wave rows = BM/2)
    constexpr int NF = BN / 64;            // B-frags per wave (wave cols = BN/4)
    constexpr int A_OPS = BM / 64;         // gload_lds ops per A tile
    constexpr int B_OPS = BN / 64;
    constexpr int LOADS = A_OPS + B_OPS;   // per-STAGE in-flight count

    const int e = blockIdx.z;
    const int m0 = blockIdx.y * BM, n0 = blockIdx.x * BN;

    int mcnt = 0;
    if constexpr (MODE == 0 || MODE == 1) {
        mcnt = min(cnt[e], CAPE);
        if (m0 >= mcnt) return;
    }

    __shared__ short As[2][BM * 64];
    __shared__ short Bs[2][BN * 64];

    const int tid = threadIdx.x;
    const int lane = tid & 63;
    const int wave = tid >> 6;
    const int wrM = wave >> 2;   // 0..1
    const int wrN = wave & 3;    // 0..3

    const short* Ab = Abase;
    const short* Bb = Bbase;
    if constexpr (MODE == 0) Bb += (size_t)e * NH * ND;
    if constexpr (MODE == 1) { Ab += (size_t)e * CAPE * NH; Bb += (size_t)e * ND * NH; }

    // ---- staging geometry: each op covers 64 rows (512 thr x 16B = 64x128B) --
    const int srow = tid >> 3;                 // 0..63 (row within op chunk)
    const int p = tid & 7;
    const int gcol = (p ^ (srow & 7)) * 8;     // inverse-swizzled global col
    const short* asrc[A_OPS];
    const short* bsrc[B_OPS];
    int dstA[A_OPS], dstB[B_OPS];
#pragma unroll
    for (int o = 0; o < A_OPS; o++) {
        int r = o * 64 + srow;
        if constexpr (MODE == 0) {
            int gr = min(m0 + r, mcnt - 1);
            int tok = tok_list[e * CAPE + gr];
            asrc[o] = Abase + (size_t)tok * ND + gcol;
        } else if constexpr (MODE == 1) {
            int gr = min(m0 + r, mcnt - 1);
            asrc[o] = Ab + (size_t)gr * NH + gcol;
        } else if constexpr (MODE == 2) {
            asrc[o] = Abase + (size_t)(m0 + r) * ND + gcol;
        } else {
            asrc[o] = Abase + (size_t)(m0 + r) * NHS + gcol;
        }
        dstA[o] = o * 4096 + wave * 512;
    }
#pragma unroll
    for (int o = 0; o < B_OPS; o++) {
        bsrc[o] = Bb + (size_t)(n0 + o * 64 + srow) * K + gcol;
        dstB[o] = o * 4096 + wave * 512;
    }

    auto STAGE = [&](int tt) {
        const int ko = (tt < NTILES ? tt : NTILES - 1) * 64;
        short* Ad = As[tt & 1];
        short* Bd = Bs[tt & 1];
#pragma unroll
        for (int o = 0; o < A_OPS; o++) gload_lds16(asrc[o] + ko, Ad + dstA[o]);
#pragma unroll
        for (int o = 0; o < B_OPS; o++) gload_lds16(bsrc[o] + ko, Bd + dstB[o]);
    };

    // ---- fragment read offsets (kh=0; kh=1 = off ^ 32) ----
    const int r16 = lane & 15, hi4 = lane >> 4, lo3 = lane & 7;
    const int physbase = (hi4 ^ lo3) * 8;
    int offA[MF], offB[NF];
#pragma unroll
    for (int m = 0; m < MF; m++)
        offA[m] = (wrM * (BM / 2) + m * 16 + r16) * 64 + physbase;
#pragma unroll
    for (int n = 0; n < NF; n++)
        offB[n] = (wrN * (BN / 4) + n * 16 + r16) * 64 + physbase;

    f32x4 acc[MF][NF] = {};

    STAGE(0);
    STAGE(1);

    for (int t = 0; t < NTILES; ++t) {
        const short* At = As[t & 1];
        const short* Bt = Bs[t & 1];
        // tile t's LOADS (oldest) complete; tile t+1's LOADS stay in flight
        if constexpr (LOADS == 6)
            asm volatile("s_waitcnt vmcnt(6)" ::: "memory");
        else if constexpr (LOADS == 8)
            asm volatile("s_waitcnt vmcnt(8)" ::: "memory");
        else
            asm volatile("s_waitcnt vmcnt(0)" ::: "memory");
        __builtin_amdgcn_s_barrier();
        __builtin_amdgcn_sched_barrier(0);
        // ---- phase A: k-half 0 ----
        s16x8 af[MF], bf[NF];
#pragma unroll
        for (int m = 0; m < MF; m++) af[m] = *(const s16x8*)(At + offA[m]);
#pragma unroll
        for (int n = 0; n < NF; n++) bf[n] = *(const s16x8*)(Bt + offB[n]);
        asm volatile("s_waitcnt lgkmcnt(0)" ::: "memory");
        __builtin_amdgcn_sched_barrier(0);
        __builtin_amdgcn_s_setprio(1);
#pragma unroll
        for (int m = 0; m < MF; m++)
#pragma unroll
            for (int n = 0; n < NF; n++)
                acc[m][n] = __builtin_amdgcn_mfma_f32_16x16x32_bf16(af[m], bf[n], acc[m][n], 0, 0, 0);
        __builtin_amdgcn_s_setprio(0);
        // ---- phase B: k-half 1 ----
        s16x8 ag[MF], bg[NF];
#pragma unroll
        for (int m = 0; m < MF; m++) ag[m] = *(const s16x8*)(At + (offA[m] ^ 32));
#pragma unroll
        for (int n = 0; n < NF; n++) bg[n] = *(const s16x8*)(Bt + (offB[n] ^ 32));
        asm volatile("s_waitcnt lgkmcnt(0)" ::: "memory");
        __builtin_amdgcn_sched_barrier(0);
        __builtin_amdgcn_s_barrier();        // all waves done reading buf[t&1]
        __builtin_amdgcn_sched_barrier(0);
        STAGE(t + 2);                        // lands after all reads retired
        __builtin_amdgcn_s_setprio(1);
#pragma unroll
        for (int m = 0; m < MF; m++)
#pragma unroll
            for (int n = 0; n < NF; n++)
                acc[m][n] = __builtin_amdgcn_mfma_f32_16x16x32_bf16(ag[m], bg[n], acc[m][n], 0, 0, 0);
        __builtin_amdgcn_s_setprio(0);
    }

    // ---- epilogue ----  C mapping: col = lane&15, row = (lane>>4)*4 + reg
    const int r0 = (lane >> 4) * 4;
    const int cc = lane & 15;

    if constexpr (MODE == 0 || MODE == 2) {
#pragma unroll
        for (int i = 0; i < MF; i++)
#pragma unroll
            for (int j = 0; j < NF; j++)
#pragma unroll
                for (int v = 0; v < 4; v++) {
                    int row = wrM * (BM / 2) + i * 16 + r0 + v;
                    int col = wrN * (BN / 4) + j * 16 + cc;
                    float val = acc[i][j][v];
                    float r = fmaxf(val, 0.f);
                    val = r * r;
                    if constexpr (MODE == 0)
                        Hout[((size_t)e * CAPE + m0 + row) * NH + (n0 + col)] = f2bf(val);
                    else
                        Hout[(size_t)(m0 + row) * NHS + (n0 + col)] = f2bf(val);
                }
    } else if constexpr (MODE == 3) {
#pragma unroll
        for (int i = 0; i < MF; i++)
#pragma unroll
            for (int j = 0; j < NF; j++)
#pragma unroll
                for (int v = 0; v < 4; v++) {
                    int row = wrM * (BM / 2) + i * 16 + r0 + v;
                    int col = wrN * (BN / 4) + j * 16 + cc;
                    out[(size_t)(m0 + row) * ND + (n0 + col)] = acc[i][j][v];
                }
    } else {  // MODE 1: bf16 store to Ybuf, valid rows only
#pragma unroll
        for (int i = 0; i < MF; i++)
#pragma unroll
            for (int v = 0; v < 4; v++) {
                int row = wrM * (BM / 2) + i * 16 + r0 + v;
                int grow = m0 + row;
                if (grow < mcnt) {
#pragma unroll
                    for (int j = 0; j < NF; j++) {
                        int col = wrN * (BN / 4) + j * 16 + cc;
                        Hout[((size_t)e * CAPE + grow) * ND + (n0 + col)] = f2bf(acc[i][j][v]);
                    }
                }
            }
    }
}

// ---------------------------------------------------------------------------
extern "C" void kernel_launch(void* const* d_in, const int* in_sizes, int n_in,
                              void* d_out, int out_size, void* d_ws, size_t ws_size,
                              hipStream_t stream) {
    const float* X    = (const float*)d_in[0];
    const float* Gw   = (const float*)d_in[1];
    const float* bias = (const float*)d_in[2];
    const float* up_w = (const float*)d_in[3];
    const float* dn_w = (const float*)d_in[4];
    const float* sup  = (const float*)d_in[5];
    const float* sdn  = (const float*)d_in[6];
    float* out = (float*)d_out;

    char* ws = (char*)d_ws;
    size_t off = 0;
    auto alloc = [&](size_t bytes) -> void* {
        off = (off + 255) & ~(size_t)255;
        void* p = ws + off;
        off += bytes;
        return p;
    };
    int*   cnt      = (int*)  alloc(NE * 4);
    int*   topk_idx = (int*)  alloc((size_t)NT * NK * 4);
    float* topk_w   = (float*)alloc((size_t)NT * NK * 4);
    int*   pos_list = (int*)  alloc((size_t)NT * NK * 4);
    int*   tok_list = (int*)  alloc((size_t)NE * CAPE * 4);
    short* Hbuf     = (short*)alloc((size_t)NE * CAPE * NH * 2);   // 64 MB
    short* Sbuf     = (short*)alloc((size_t)NT * NHS * 2);         // 32 MB
    short* Xbf      = (short*)alloc((size_t)NT * ND * 2);          // 16 MB
    short* up_bf    = (short*)alloc((size_t)NE * NH * ND * 2);     // 128 MB
    short* dn_bf    = (short*)alloc((size_t)NE * ND * NH * 2);     // 128 MB
    short* sup_bf   = (short*)alloc((size_t)NHS * ND * 2);         // 16 MB
    short* sdn_bf   = (short*)alloc((size_t)ND * NHS * 2);         // 16 MB
    // Ybuf (128 MB) aliases [Xbf .. up_bf] — both dead once MODE0+MODE2 ran.
    short* Ybuf     = Xbf;

    gate_kernel<<<dim3(NT / 4), dim3(256), 0, stream>>>(X, Gw, bias, topk_idx, topk_w);
    zero_cnt<<<dim3(1), dim3(64), 0, stream>>>(cnt);
    dispatch_kernel<<<dim3(NT * NK / 256), dim3(256), 0, stream>>>(
        topk_idx, cnt, tok_list, pos_list);

    // bulk f32 -> bf16 conversion
    cvt_f2bf<<<dim3(1024), dim3(256), 0, stream>>>(X,    Xbf,    NT * ND / 8);
    cvt_f2bf<<<dim3(2048), dim3(256), 0, stream>>>(up_w, up_bf,  NE * NH * ND / 8);
    cvt_f2bf<<<dim3(2048), dim3(256), 0, stream>>>(dn_w, dn_bf,  NE * ND * NH / 8);
    cvt_f2bf<<<dim3(1024), dim3(256), 0, stream>>>(sup,  sup_bf, NHS * ND / 8);
    cvt_f2bf<<<dim3(1024), dim3(256), 0, stream>>>(sdn,  sdn_bf, ND * NHS / 8);

    // routed up: X gathered -> Hbuf. BM=128 for per-expert granularity.
    moe_gemm8<0, 128, 256><<<dim3(NH / 256, CAPE / 128, NE), dim3(512), 0, stream>>>(
        Xbf, up_bf, cnt, tok_list, Hbuf, nullptr);
    // shared up: X -> Sbuf. 256x256, 256 blocks = 1/CU.
    moe_gemm8<2, 256, 256><<<dim3(NHS / 256, NT / 256, 1), dim3(512), 0, stream>>>(
        Xbf, sup_bf, nullptr, nullptr, Sbuf, nullptr);
    // shared down: Sbuf -> out. 256x128 -> 16x16 = 256 blocks (was 128).
    moe_gemm8<3, 256, 128><<<dim3(ND / 128, NT / 256, 1), dim3(512), 0, stream>>>(
        Sbuf, sdn_bf, nullptr, nullptr, nullptr, out);
    // routed down: Hbuf -> Ybuf. BM=128.
    moe_gemm8<1, 128, 256><<<dim3(ND / 256, CAPE / 128, NE), dim3(512), 0, stream>>>(
        Hbuf, dn_bf, cnt, tok_list, Ybuf, nullptr);
    // combine: out += sum_k w_k * Ybuf[e_k, pos_k]
    combine_kernel<<<dim3(NT), dim3(256), 0, stream>>>(
        topk_idx, topk_w, pos_list, Ybuf, out);
}

// Round 8
// 731.613 us; speedup vs baseline: 1.0799x; 1.0799x over previous
//
#include <hip/hip_runtime.h>

#define NE 32
#define NG 8
#define NK 4
#define ND 2048
#define NH 1024
#define NHS 4096
#define CAPE 1024
#define NT 4096

typedef float f32x4 __attribute__((ext_vector_type(4)));
typedef short s16x8 __attribute__((ext_vector_type(8)));

__device__ __forceinline__ short f2bf(float f) {
    return __builtin_bit_cast(short, (__bf16)f);
}
__device__ __forceinline__ float bf2f(short h) {
    return __builtin_bit_cast(float, ((unsigned)(unsigned short)h) << 16);
}

__device__ __forceinline__ void gload_lds16(const void* g, void* l) {
    __builtin_amdgcn_global_load_lds(
        (const __attribute__((address_space(1))) void*)g,
        (__attribute__((address_space(3))) void*)l, 16, 0, 0);
}

// ---------------------------------------------------------------------------
// Kernel 1: gating. One wave per token. fp32 logits, sigmoid, grouped top-k.
// ---------------------------------------------------------------------------
__global__ __launch_bounds__(256) void gate_kernel(
    const float* __restrict__ X, const float* __restrict__ Gw,
    const float* __restrict__ bias,
    int* __restrict__ topk_idx, float* __restrict__ topk_w)
{
    const int lane = threadIdx.x & 63;
    const int t = blockIdx.x * 4 + (threadIdx.x >> 6);
    const float* x = X + (size_t)t * ND;

    float xr[32];
#pragma unroll
    for (int i = 0; i < 32; i++) xr[i] = x[lane + i * 64];

    float scores[32];
#pragma unroll
    for (int e = 0; e < 32; e++) {
        const float* w = Gw + (size_t)e * ND;
        float a = 0.f;
#pragma unroll
        for (int i = 0; i < 32; i++) a = fmaf(xr[i], w[lane + i * 64], a);
#pragma unroll
        for (int s = 32; s > 0; s >>= 1) a += __shfl_xor(a, s);
        scores[e] = 1.0f / (1.0f + expf(-a));
    }

    float sc_c[32];
#pragma unroll
    for (int e = 0; e < 32; e++) sc_c[e] = scores[e] + bias[e];

    float gs[8];
#pragma unroll
    for (int g = 0; g < 8; g++) {
        float a = sc_c[4 * g], b = sc_c[4 * g + 1], c = sc_c[4 * g + 2], d = sc_c[4 * g + 3];
        float hi1 = fmaxf(a, b), lo1 = fminf(a, b);
        float hi2 = fmaxf(c, d), lo2 = fminf(c, d);
        float m1 = fmaxf(hi1, hi2);
        float m2 = fmaxf(fminf(hi1, hi2), fmaxf(lo1, lo2));
        gs[g] = m1 + m2;
    }

    unsigned gsel = 0;
#pragma unroll
    for (int it = 0; it < 4; it++) {
        int best = -1; float bv = -1e30f;
#pragma unroll
        for (int g = 0; g < 8; g++) {
            bool avail = !((gsel >> g) & 1);
            if (avail && gs[g] > bv) { bv = gs[g]; best = g; }
        }
        gsel |= 1u << best;
    }

    unsigned esel = 0;
    int idxs[4]; float wts[4];
#pragma unroll
    for (int it = 0; it < 4; it++) {
        int best = -1; float bv = -1e30f, braw = 0.f;
#pragma unroll
        for (int e = 0; e < 32; e++) {
            float mv = ((gsel >> (e >> 2)) & 1) ? sc_c[e] : 0.0f;
            bool avail = !((esel >> e) & 1);
            if (avail && mv > bv) { bv = mv; best = e; braw = scores[e]; }
        }
        esel |= 1u << best;
        idxs[it] = best; wts[it] = braw;
    }

    float s = wts[0] + wts[1] + wts[2] + wts[3] + 1e-20f;
    if (lane == 0) {
#pragma unroll
        for (int k = 0; k < 4; k++) {
            topk_idx[t * 4 + k] = idxs[k];
            topk_w[t * 4 + k] = wts[k] / s * 2.5f;
        }
    }
}

// ---------------------------------------------------------------------------
__global__ void zero_cnt(int* cnt) {
    if (threadIdx.x < NE) cnt[threadIdx.x] = 0;
}

__global__ void dispatch_kernel(const int* __restrict__ topk_idx,
                                int* __restrict__ cnt,
                                int* __restrict__ tok_list,
                                int* __restrict__ pos_list)
{
    int i = blockIdx.x * 256 + threadIdx.x;
    int e = topk_idx[i];
    int t = i >> 2;
    int pos = atomicAdd(&cnt[e], 1);
    pos_list[i] = pos;
    if (pos < CAPE) {
        tok_list[e * CAPE + pos] = t;
    }
}

// ---------------------------------------------------------------------------
// f32 -> bf16 bulk conversion (8 elems / thread / iter, grid-stride)
// ---------------------------------------------------------------------------
__global__ __launch_bounds__(256) void cvt_f2bf(const float* __restrict__ in,
                                                short* __restrict__ out, int n8)
{
    int i = blockIdx.x * 256 + threadIdx.x;
    int stride = gridDim.x * 256;
    for (; i < n8; i += stride) {
        const f32x4* p = (const f32x4*)(in + (size_t)i * 8);
        f32x4 a = p[0], b = p[1];
        s16x8 h;
        h[0] = f2bf(a[0]); h[1] = f2bf(a[1]); h[2] = f2bf(a[2]); h[3] = f2bf(a[3]);
        h[4] = f2bf(b[0]); h[5] = f2bf(b[1]); h[6] = f2bf(b[2]); h[7] = f2bf(b[3]);
        *(s16x8*)(out + (size_t)i * 8) = h;
    }
}

// ---------------------------------------------------------------------------
// Combine: out[t] = shared_down[t] (already in out) + sum_k w_k * Ybuf[e_k,pos_k]
// ---------------------------------------------------------------------------
__global__ __launch_bounds__(256) void combine_kernel(
    const int* __restrict__ topk_idx, const float* __restrict__ topk_w,
    const int* __restrict__ pos_list,
    const short* __restrict__ Ybuf, float* __restrict__ out)
{
    const int t = blockIdx.x;
    const int d0 = threadIdx.x * 8;

    int e[NK], p[NK]; float w[NK];
#pragma unroll
    for (int k = 0; k < NK; k++) {
        e[k] = topk_idx[t * NK + k];
        p[k] = pos_list[t * NK + k];
        w[k] = topk_w[t * NK + k];
    }

    float* orow = out + (size_t)t * ND + d0;
    f32x4 o0 = *(f32x4*)(orow);
    f32x4 o1 = *(f32x4*)(orow + 4);

#pragma unroll
    for (int k = 0; k < NK; k++) {
        if (p[k] < CAPE) {
            s16x8 y = *(const s16x8*)(Ybuf + ((size_t)e[k] * CAPE + p[k]) * ND + d0);
            o0[0] = fmaf(w[k], bf2f(y[0]), o0[0]);
            o0[1] = fmaf(w[k], bf2f(y[1]), o0[1]);
            o0[2] = fmaf(w[k], bf2f(y[2]), o0[2]);
            o0[3] = fmaf(w[k], bf2f(y[3]), o0[3]);
            o1[0] = fmaf(w[k], bf2f(y[4]), o1[0]);
            o1[1] = fmaf(w[k], bf2f(y[5]), o1[1]);
            o1[2] = fmaf(w[k], bf2f(y[6]), o1[2]);
            o1[3] = fmaf(w[k], bf2f(y[7]), o1[3]);
        }
    }
    *(f32x4*)(orow) = o0;
    *(f32x4*)(orow + 4) = o1;
}

// ---------------------------------------------------------------------------
// 8-wave GEMM: BM x BN tile, BK=32, QUAD-buffered LDS, 3-tiles-ahead prefetch,
// one barrier + counted vmcnt(2L) per K-tile, setprio around MFMA cluster.
// Swizzle: row r, k-slot s (16B) stored at phys slot s ^ ((r ^ r>>2) & 3);
// staging fetches the inverse-permuted global column (both-sides, rule #21).
// MODE 0: routed up   (A = Xbf gathered,  B = up_bf[e],  out = relu2 -> Hbuf)
// MODE 1: routed down (A = Hbuf[e],       B = dn_bf[e],  out = Ybuf bf16)
// MODE 2: shared up   (A = Xbf,           B = sup_bf,    out = relu2 -> Sbuf)
// MODE 3: shared down (A = Sbuf,          B = sdn_bf,    out = f32 write)
// ---------------------------------------------------------------------------
template <int MODE, int BM, int BN>
__global__ __launch_bounds__(512, 2) void moe_gemm8(
    const short* __restrict__ Abase, const short* __restrict__ Bbase,
    const int* __restrict__ cnt, const int* __restrict__ tok_list,
    short* __restrict__ Hout, float* __restrict__ out)
{
    constexpr int K = (MODE == 0) ? ND : (MODE == 1) ? NH : (MODE == 2) ? ND : NHS;
    constexpr int NTILES = K / 32;
    constexpr int MF = BM / 32;            // A-frags per wave (wave rows = BM/2)
    constexpr int NF = BN / 64;            // B-frags per wave (wave cols = BN/4)
    constexpr int A_OPS = BM / 128;        // staging ops (128 rows x 64B each)
    constexpr int B_OPS = BN / 128;
    constexpr int LOADS = A_OPS + B_OPS;   // gload_lds per thread per tile

    const int e = blockIdx.z;
    const int m0 = blockIdx.y * BM, n0 = blockIdx.x * BN;

    int mcnt = 0;
    if constexpr (MODE == 0 || MODE == 1) {
        mcnt = min(cnt[e], CAPE);
        if (m0 >= mcnt) return;
    }

    __shared__ short As[4][BM * 32];
    __shared__ short Bs[4][BN * 32];

    const int tid = threadIdx.x;
    const int lane = tid & 63;
    const int wave = tid >> 6;
    const int wrM = wave >> 2;   // 0..1
    const int wrN = wave & 3;    // 0..3

    const short* Ab = Abase;
    const short* Bb = Bbase;
    if constexpr (MODE == 0) Bb += (size_t)e * NH * ND;
    if constexpr (MODE == 1) { Ab += (size_t)e * CAPE * NH; Bb += (size_t)e * ND * NH; }

    // ---- staging geometry: op = 128 rows x 32 elems (512 thr x 16B) ----
    const int srow = tid >> 2;                       // 0..127 row within op
    const int p = tid & 3;                           // phys 16B slot 0..3
    const int swzs = (srow ^ (srow >> 2)) & 3;       // swizzle key (row-dependent)
    const int gcol = (p ^ swzs) * 8;                 // inverse-swizzled global col
    const short* asrc[A_OPS];
    const short* bsrc[B_OPS];
    int dstA[A_OPS], dstB[B_OPS];
#pragma unroll
    for (int o = 0; o < A_OPS; o++) {
        int r = o * 128 + srow;
        if constexpr (MODE == 0) {
            int gr = min(m0 + r, mcnt - 1);
            int tok = tok_list[e * CAPE + gr];
            asrc[o] = Abase + (size_t)tok * ND + gcol;
        } else if constexpr (MODE == 1) {
            int gr = min(m0 + r, mcnt - 1);
            asrc[o] = Ab + (size_t)gr * NH + gcol;
        } else if constexpr (MODE == 2) {
            asrc[o] = Abase + (size_t)(m0 + r) * ND + gcol;
        } else {
            asrc[o] = Abase + (size_t)(m0 + r) * NHS + gcol;
        }
        dstA[o] = o * 4096 + wave * 512;             // linear: thread tid -> tid*8 elems
    }
#pragma unroll
    for (int o = 0; o < B_OPS; o++) {
        bsrc[o] = Bb + (size_t)(n0 + o * 128 + srow) * K + gcol;
        dstB[o] = o * 4096 + wave * 512;
    }

    auto STAGE = [&](int tt) {
        const int ko = (tt < NTILES ? tt : NTILES - 1) * 32;
        short* Ad = As[tt & 3];
        short* Bd = Bs[tt & 3];
#pragma unroll
        for (int o = 0; o < A_OPS; o++) gload_lds16(asrc[o] + ko, Ad + dstA[o]);
#pragma unroll
        for (int o = 0; o < B_OPS; o++) gload_lds16(bsrc[o] + ko, Bd + dstB[o]);
    };

    // ---- fragment read offsets ----
    const int r16 = lane & 15;                       // row within frag
    const int kslot = lane >> 4;                     // logical k-slot 0..3
    const int rswz = (r16 ^ (r16 >> 2)) & 3;
    const int physcol = (kslot ^ rswz) * 8;
    int offA[MF], offB[NF];
#pragma unroll
    for (int m = 0; m < MF; m++)
        offA[m] = (wrM * (BM / 2) + m * 16 + r16) * 32 + physcol;
#pragma unroll
    for (int n = 0; n < NF; n++)
        offB[n] = (wrN * (BN / 4) + n * 16 + r16) * 32 + physcol;

    f32x4 acc[MF][NF] = {};

    STAGE(0); STAGE(1); STAGE(2);

    for (int t = 0; t < NTILES; ++t) {
        const short* At = As[t & 3];
        const short* Bt = Bs[t & 3];
        // wait tile t's LOADS (oldest); tiles t+1,t+2 stay in flight
        if constexpr (LOADS == 4)
            asm volatile("s_waitcnt vmcnt(8)" ::: "memory");
        else if constexpr (LOADS == 3)
            asm volatile("s_waitcnt vmcnt(6)" ::: "memory");
        else if constexpr (LOADS == 2)
            asm volatile("s_waitcnt vmcnt(4)" ::: "memory");
        else
            asm volatile("s_waitcnt vmcnt(0)" ::: "memory");
        __builtin_amdgcn_s_barrier();
        __builtin_amdgcn_sched_barrier(0);

        s16x8 af[MF], bf[NF];
#pragma unroll
        for (int m = 0; m < MF; m++) af[m] = *(const s16x8*)(At + offA[m]);
#pragma unroll
        for (int n = 0; n < NF; n++) bf[n] = *(const s16x8*)(Bt + offB[n]);

        STAGE(t + 3);                    // buf[(t+3)&3]: reads retired by barrier above

        asm volatile("s_waitcnt lgkmcnt(0)" ::: "memory");
        __builtin_amdgcn_sched_barrier(0);
        __builtin_amdgcn_s_setprio(1);
#pragma unroll
        for (int m = 0; m < MF; m++)
#pragma unroll
            for (int n = 0; n < NF; n++)
                acc[m][n] = __builtin_amdgcn_mfma_f32_16x16x32_bf16(af[m], bf[n], acc[m][n], 0, 0, 0);
        __builtin_amdgcn_s_setprio(0);
    }

    // ---- epilogue ----  C mapping: col = lane&15, row = (lane>>4)*4 + reg
    const int r0 = (lane >> 4) * 4;
    const int cc = lane & 15;

    if constexpr (MODE == 0 || MODE == 2) {
#pragma unroll
        for (int i = 0; i < MF; i++)
#pragma unroll
            for (int j = 0; j < NF; j++)
#pragma unroll
                for (int v = 0; v < 4; v++) {
                    int row = wrM * (BM / 2) + i * 16 + r0 + v;
                    int col = wrN * (BN / 4) + j * 16 + cc;
                    float val = acc[i][j][v];
                    float r = fmaxf(val, 0.f);
                    val = r * r;
                    if constexpr (MODE == 0)
                        Hout[((size_t)e * CAPE + m0 + row) * NH + (n0 + col)] = f2bf(val);
                    else
                        Hout[(size_t)(m0 + row) * NHS + (n0 + col)] = f2bf(val);
                }
    } else if constexpr (MODE == 3) {
#pragma unroll
        for (int i = 0; i < MF; i++)
#pragma unroll
            for (int j = 0; j < NF; j++)
#pragma unroll
                for (int v = 0; v < 4; v++) {
                    int row = wrM * (BM / 2) + i * 16 + r0 + v;
                    int col = wrN * (BN / 4) + j * 16 + cc;
                    out[(size_t)(m0 + row) * ND + (n0 + col)] = acc[i][j][v];
                }
    } else {  // MODE 1: bf16 store to Ybuf, valid rows only
#pragma unroll
        for (int i = 0; i < MF; i++)
#pragma unroll
            for (int v = 0; v < 4; v++) {
                int row = wrM * (BM / 2) + i * 16 + r0 + v;
                int grow = m0 + row;
                if (grow < mcnt) {
#pragma unroll
                    for (int j = 0; j < NF; j++) {
                        int col = wrN * (BN / 4) + j * 16 + cc;
                        Hout[((size_t)e * CAPE + grow) * ND + (n0 + col)] = f2bf(acc[i][j][v]);
                    }
                }
            }
    }
}

// ---------------------------------------------------------------------------
extern "C" void kernel_launch(void* const* d_in, const int* in_sizes, int n_in,
                              void* d_out, int out_size, void* d_ws, size_t ws_size,
                              hipStream_t stream) {
    const float* X    = (const float*)d_in[0];
    const float* Gw   = (const float*)d_in[1];
    const float* bias = (const float*)d_in[2];
    const float* up_w = (const float*)d_in[3];
    const float* dn_w = (const float*)d_in[4];
    const float* sup  = (const float*)d_in[5];
    const float* sdn  = (const float*)d_in[6];
    float* out = (float*)d_out;

    char* ws = (char*)d_ws;
    size_t off = 0;
    auto alloc = [&](size_t bytes) -> void* {
        off = (off + 255) & ~(size_t)255;
        void* p = ws + off;
        off += bytes;
        return p;
    };
    int*   cnt      = (int*)  alloc(NE * 4);
    int*   topk_idx = (int*)  alloc((size_t)NT * NK * 4);
    float* topk_w   = (float*)alloc((size_t)NT * NK * 4);
    int*   pos_list = (int*)  alloc((size_t)NT * NK * 4);
    int*   tok_list = (int*)  alloc((size_t)NE * CAPE * 4);
    short* Hbuf     = (short*)alloc((size_t)NE * CAPE * NH * 2);   // 64 MB
    short* Sbuf     = (short*)alloc((size_t)NT * NHS * 2);         // 32 MB
    short* Xbf      = (short*)alloc((size_t)NT * ND * 2);          // 16 MB
    short* up_bf    = (short*)alloc((size_t)NE * NH * ND * 2);     // 128 MB
    short* dn_bf    = (short*)alloc((size_t)NE * ND * NH * 2);     // 128 MB
    short* sup_bf   = (short*)alloc((size_t)NHS * ND * 2);         // 16 MB
    short* sdn_bf   = (short*)alloc((size_t)ND * NHS * 2);         // 16 MB
    // Ybuf (128 MB) aliases [Xbf .. up_bf] — both dead once MODE0+MODE2 ran.
    short* Ybuf     = Xbf;

    gate_kernel<<<dim3(NT / 4), dim3(256), 0, stream>>>(X, Gw, bias, topk_idx, topk_w);
    zero_cnt<<<dim3(1), dim3(64), 0, stream>>>(cnt);
    dispatch_kernel<<<dim3(NT * NK / 256), dim3(256), 0, stream>>>(
        topk_idx, cnt, tok_list, pos_list);

    // bulk f32 -> bf16 conversion
    cvt_f2bf<<<dim3(1024), dim3(256), 0, stream>>>(X,    Xbf,    NT * ND / 8);
    cvt_f2bf<<<dim3(2048), dim3(256), 0, stream>>>(up_w, up_bf,  NE * NH * ND / 8);
    cvt_f2bf<<<dim3(2048), dim3(256), 0, stream>>>(dn_w, dn_bf,  NE * ND * NH / 8);
    cvt_f2bf<<<dim3(1024), dim3(256), 0, stream>>>(sup,  sup_bf, NHS * ND / 8);
    cvt_f2bf<<<dim3(1024), dim3(256), 0, stream>>>(sdn,  sdn_bf, ND * NHS / 8);

    // routed up: X gathered -> Hbuf (256x256)
    moe_gemm8<0, 256, 256><<<dim3(NH / 256, CAPE / 256, NE), dim3(512), 0, stream>>>(
        Xbf, up_bf, cnt, tok_list, Hbuf, nullptr);
    // shared up: X -> Sbuf (256x256, 256 blocks = 1/CU)
    moe_gemm8<2, 256, 256><<<dim3(NHS / 256, NT / 256, 1), dim3(512), 0, stream>>>(
        Xbf, sup_bf, nullptr, nullptr, Sbuf, nullptr);
    // shared down: Sbuf -> out (256x128 -> 256 blocks)
    moe_gemm8<3, 256, 128><<<dim3(ND / 128, NT / 256, 1), dim3(512), 0, stream>>>(
        Sbuf, sdn_bf, nullptr, nullptr, nullptr, out);
    // routed down: Hbuf -> Ybuf (256x256)
    moe_gemm8<1, 256, 256><<<dim3(ND / 256, CAPE / 256, NE), dim3(512), 0, stream>>>(
        Hbuf, dn_bf, cnt, tok_list, Ybuf, nullptr);
    // combine: out += sum_k w_k * Ybuf[e_k, pos_k]
    combine_kernel<<<dim3(NT), dim3(256), 0, stream>>>(
        topk_idx, topk_w, pos_list, Ybuf, out);
}

// Round 9
// 678.458 us; speedup vs baseline: 1.1645x; 1.0783x over previous
//
#include <hip/hip_runtime.h>

#define NE 32
#define NG 8
#define NK 4
#define ND 2048
#define NH 1024
#define NHS 4096
#define CAPE 1024
#define NT 4096

typedef float f32x4 __attribute__((ext_vector_type(4)));
typedef short s16x8 __attribute__((ext_vector_type(8)));

__device__ __forceinline__ short f2bf(float f) {
    return __builtin_bit_cast(short, (__bf16)f);
}
__device__ __forceinline__ float bf2f(short h) {
    return __builtin_bit_cast(float, ((unsigned)(unsigned short)h) << 16);
}

__device__ __forceinline__ void gload_lds16(const void* g, void* l) {
    __builtin_amdgcn_global_load_lds(
        (const __attribute__((address_space(1))) void*)g,
        (__attribute__((address_space(3))) void*)l, 16, 0, 0);
}

// ---------------------------------------------------------------------------
// Kernel 1: gating. One wave per token. fp32 logits, sigmoid, grouped top-k.
// ---------------------------------------------------------------------------
__global__ __launch_bounds__(256) void gate_kernel(
    const float* __restrict__ X, const float* __restrict__ Gw,
    const float* __restrict__ bias,
    int* __restrict__ topk_idx, float* __restrict__ topk_w)
{
    const int lane = threadIdx.x & 63;
    const int t = blockIdx.x * 4 + (threadIdx.x >> 6);
    const float* x = X + (size_t)t * ND;

    float xr[32];
#pragma unroll
    for (int i = 0; i < 32; i++) xr[i] = x[lane + i * 64];

    float scores[32];
#pragma unroll
    for (int e = 0; e < 32; e++) {
        const float* w = Gw + (size_t)e * ND;
        float a = 0.f;
#pragma unroll
        for (int i = 0; i < 32; i++) a = fmaf(xr[i], w[lane + i * 64], a);
#pragma unroll
        for (int s = 32; s > 0; s >>= 1) a += __shfl_xor(a, s);
        scores[e] = 1.0f / (1.0f + expf(-a));
    }

    float sc_c[32];
#pragma unroll
    for (int e = 0; e < 32; e++) sc_c[e] = scores[e] + bias[e];

    float gs[8];
#pragma unroll
    for (int g = 0; g < 8; g++) {
        float a = sc_c[4 * g], b = sc_c[4 * g + 1], c = sc_c[4 * g + 2], d = sc_c[4 * g + 3];
        float hi1 = fmaxf(a, b), lo1 = fminf(a, b);
        float hi2 = fmaxf(c, d), lo2 = fminf(c, d);
        float m1 = fmaxf(hi1, hi2);
        float m2 = fmaxf(fminf(hi1, hi2), fmaxf(lo1, lo2));
        gs[g] = m1 + m2;
    }

    unsigned gsel = 0;
#pragma unroll
    for (int it = 0; it < 4; it++) {
        int best = -1; float bv = -1e30f;
#pragma unroll
        for (int g = 0; g < 8; g++) {
            bool avail = !((gsel >> g) & 1);
            if (avail && gs[g] > bv) { bv = gs[g]; best = g; }
        }
        gsel |= 1u << best;
    }

    unsigned esel = 0;
    int idxs[4]; float wts[4];
#pragma unroll
    for (int it = 0; it < 4; it++) {
        int best = -1; float bv = -1e30f, braw = 0.f;
#pragma unroll
        for (int e = 0; e < 32; e++) {
            float mv = ((gsel >> (e >> 2)) & 1) ? sc_c[e] : 0.0f;
            bool avail = !((esel >> e) & 1);
            if (avail && mv > bv) { bv = mv; best = e; braw = scores[e]; }
        }
        esel |= 1u << best;
        idxs[it] = best; wts[it] = braw;
    }

    float s = wts[0] + wts[1] + wts[2] + wts[3] + 1e-20f;
    if (lane == 0) {
#pragma unroll
        for (int k = 0; k < 4; k++) {
            topk_idx[t * 4 + k] = idxs[k];
            topk_w[t * 4 + k] = wts[k] / s * 2.5f;
        }
    }
}

// ---------------------------------------------------------------------------
__global__ void zero_cnt(int* cnt) {
    if (threadIdx.x < NE) cnt[threadIdx.x] = 0;
}

__global__ void dispatch_kernel(const int* __restrict__ topk_idx,
                                int* __restrict__ cnt,
                                int* __restrict__ tok_list,
                                int* __restrict__ pos_list)
{
    int i = blockIdx.x * 256 + threadIdx.x;
    int e = topk_idx[i];
    int t = i >> 2;
    int pos = atomicAdd(&cnt[e], 1);
    pos_list[i] = pos;
    if (pos < CAPE) {
        tok_list[e * CAPE + pos] = t;
    }
}

// ---------------------------------------------------------------------------
// f32 -> bf16 bulk conversion (8 elems / thread / iter, grid-stride)
// ---------------------------------------------------------------------------
__global__ __launch_bounds__(256) void cvt_f2bf(const float* __restrict__ in,
                                                short* __restrict__ out, int n8)
{
    int i = blockIdx.x * 256 + threadIdx.x;
    int stride = gridDim.x * 256;
    for (; i < n8; i += stride) {
        const f32x4* p = (const f32x4*)(in + (size_t)i * 8);
        f32x4 a = p[0], b = p[1];
        s16x8 h;
        h[0] = f2bf(a[0]); h[1] = f2bf(a[1]); h[2] = f2bf(a[2]); h[3] = f2bf(a[3]);
        h[4] = f2bf(b[0]); h[5] = f2bf(b[1]); h[6] = f2bf(b[2]); h[7] = f2bf(b[3]);
        *(s16x8*)(out + (size_t)i * 8) = h;
    }
}

// ---------------------------------------------------------------------------
// Combine: out[t] = shared_down[t] (already in out) + sum_k w_k * Ybuf[e_k,pos_k]
// ---------------------------------------------------------------------------
__global__ __launch_bounds__(256) void combine_kernel(
    const int* __restrict__ topk_idx, const float* __restrict__ topk_w,
    const int* __restrict__ pos_list,
    const short* __restrict__ Ybuf, float* __restrict__ out)
{
    const int t = blockIdx.x;
    const int d0 = threadIdx.x * 8;

    int e[NK], p[NK]; float w[NK];
#pragma unroll
    for (int k = 0; k < NK; k++) {
        e[k] = topk_idx[t * NK + k];
        p[k] = pos_list[t * NK + k];
        w[k] = topk_w[t * NK + k];
    }

    float* orow = out + (size_t)t * ND + d0;
    f32x4 o0 = *(f32x4*)(orow);
    f32x4 o1 = *(f32x4*)(orow + 4);

#pragma unroll
    for (int k = 0; k < NK; k++) {
        if (p[k] < CAPE) {
            s16x8 y = *(const s16x8*)(Ybuf + ((size_t)e[k] * CAPE + p[k]) * ND + d0);
            o0[0] = fmaf(w[k], bf2f(y[0]), o0[0]);
            o0[1] = fmaf(w[k], bf2f(y[1]), o0[1]);
            o0[2] = fmaf(w[k], bf2f(y[2]), o0[2]);
            o0[3] = fmaf(w[k], bf2f(y[3]), o0[3]);
            o1[0] = fmaf(w[k], bf2f(y[4]), o1[0]);
            o1[1] = fmaf(w[k], bf2f(y[5]), o1[1]);
            o1[2] = fmaf(w[k], bf2f(y[6]), o1[2]);
            o1[3] = fmaf(w[k], bf2f(y[7]), o1[3]);
        }
    }
    *(f32x4*)(orow) = o0;
    *(f32x4*)(orow + 4) = o1;
}

// ---------------------------------------------------------------------------
// 4-wave GEMM: 128x128 tile, BK=64, double-buffered LDS (64 KB total ->
// 2 blocks/CU for cross-block latency overlap), counted vmcnt(8) across raw
// barriers (R6-verified schedule), setprio around MFMA, R6's zero-conflict
// both-sides XOR swizzle (phys 16B slot = slot ^ (row&7); inverse on source).
// MODE 0: routed up   (A = Xbf gathered,  B = up_bf[e],  out = relu2 -> Hbuf)
// MODE 1: routed down (A = Hbuf[e],       B = dn_bf[e],  out = Ybuf bf16)
// MODE 2: shared up   (A = Xbf,           B = sup_bf,    out = relu2 -> Sbuf)
// MODE 3: shared down (A = Sbuf,          B = sdn_bf,    out = f32 write)
// ---------------------------------------------------------------------------
template <int MODE>
__global__ __launch_bounds__(256, 2) void moe_gemm4(
    const short* __restrict__ Abase, const short* __restrict__ Bbase,
    const int* __restrict__ cnt, const int* __restrict__ tok_list,
    short* __restrict__ Hout, float* __restrict__ out)
{
    constexpr int K = (MODE == 0) ? ND : (MODE == 1) ? NH : (MODE == 2) ? ND : NHS;
    constexpr int NTILES = K / 64;

    const int e = blockIdx.z;
    const int m0 = blockIdx.y * 128, n0 = blockIdx.x * 128;

    int mcnt = 0;
    if constexpr (MODE == 0 || MODE == 1) {
        mcnt = min(cnt[e], CAPE);
        if (m0 >= mcnt) return;
    }

    __shared__ short As[2][128 * 64];
    __shared__ short Bs[2][128 * 64];

    const int tid = threadIdx.x;
    const int lane = tid & 63;
    const int wave = tid >> 6;
    const int wr = wave >> 1, wc = wave & 1;     // 2x2 wave grid, 64x64 each

    const short* Ab = Abase;
    const short* Bb = Bbase;
    if constexpr (MODE == 0) Bb += (size_t)e * NH * ND;
    if constexpr (MODE == 1) { Ab += (size_t)e * CAPE * NH; Bb += (size_t)e * ND * NH; }

    // ---- staging: op = 32 rows x 64 elems (256 thr x 16 B = 4 KB) ----
    const int srow = tid >> 3;                  // 0..31 row within op
    const int p = tid & 7;                      // phys 16B slot 0..7
    const int gcol = (p ^ (srow & 7)) * 8;      // inverse-swizzled global col
    const short* asrc[4];
    const short* bsrc[4];
    int dstoff[4];
#pragma unroll
    for (int o = 0; o < 4; o++) {
        int r = o * 32 + srow;                  // tile row 0..127
        if constexpr (MODE == 0) {
            int gr = min(m0 + r, mcnt - 1);
            int tok = tok_list[e * CAPE + gr];
            asrc[o] = Abase + (size_t)tok * ND + gcol;
        } else if constexpr (MODE == 1) {
            int gr = min(m0 + r, mcnt - 1);
            asrc[o] = Ab + (size_t)gr * NH + gcol;
        } else if constexpr (MODE == 2) {
            asrc[o] = Abase + (size_t)(m0 + r) * ND + gcol;
        } else {
            asrc[o] = Abase + (size_t)(m0 + r) * NHS + gcol;
        }
        bsrc[o] = Bb + (size_t)(n0 + o * 32 + srow) * K + gcol;
        dstoff[o] = o * 2048 + wave * 512;      // elems; + lane*8 by HW
    }

    auto STAGE = [&](int tt) {
        const int ko = (tt < NTILES ? tt : NTILES - 1) * 64;
        short* Ad = As[tt & 1];
        short* Bd = Bs[tt & 1];
#pragma unroll
        for (int o = 0; o < 4; o++) gload_lds16(asrc[o] + ko, Ad + dstoff[o]);
#pragma unroll
        for (int o = 0; o < 4; o++) gload_lds16(bsrc[o] + ko, Bd + dstoff[o]);
    };

    // ---- fragment read offsets (kh=0; kh=1 = off ^ 32) ----
    const int r16 = lane & 15;
    const int physbase = ((lane >> 4) ^ (lane & 7)) * 8;
    int offA[4], offB[4];
#pragma unroll
    for (int m = 0; m < 4; m++)
        offA[m] = (wr * 64 + m * 16 + r16) * 64 + physbase;
#pragma unroll
    for (int n = 0; n < 4; n++)
        offB[n] = (wc * 64 + n * 16 + r16) * 64 + physbase;

    f32x4 acc[4][4] = {};

    STAGE(0);
    STAGE(1);

    for (int t = 0; t < NTILES; ++t) {
        const short* At = As[t & 1];
        const short* Bt = Bs[t & 1];
        // tile t's 8 loads (oldest) complete; tile t+1's 8 stay in flight
        asm volatile("s_waitcnt vmcnt(8)" ::: "memory");
        __builtin_amdgcn_s_barrier();
        __builtin_amdgcn_sched_barrier(0);
        // ---- phase A: k-half 0 ----
        s16x8 af[4], bf[4];
#pragma unroll
        for (int m = 0; m < 4; m++) af[m] = *(const s16x8*)(At + offA[m]);
#pragma unroll
        for (int n = 0; n < 4; n++) bf[n] = *(const s16x8*)(Bt + offB[n]);
        asm volatile("s_waitcnt lgkmcnt(0)" ::: "memory");
        __builtin_amdgcn_sched_barrier(0);
        __builtin_amdgcn_s_setprio(1);
#pragma unroll
        for (int m = 0; m < 4; m++)
#pragma unroll
            for (int n = 0; n < 4; n++)
                acc[m][n] = __builtin_amdgcn_mfma_f32_16x16x32_bf16(af[m], bf[n], acc[m][n], 0, 0, 0);
        __builtin_amdgcn_s_setprio(0);
        // ---- phase B: k-half 1 ----
        s16x8 ag[4], bg[4];
#pragma unroll
        for (int m = 0; m < 4; m++) ag[m] = *(const s16x8*)(At + (offA[m] ^ 32));
#pragma unroll
        for (int n = 0; n < 4; n++) bg[n] = *(const s16x8*)(Bt + (offB[n] ^ 32));
        asm volatile("s_waitcnt lgkmcnt(0)" ::: "memory");
        __builtin_amdgcn_sched_barrier(0);
        __builtin_amdgcn_s_barrier();        // all waves done reading buf[t&1]
        __builtin_amdgcn_sched_barrier(0);
        STAGE(t + 2);                        // lands after all reads retired
        __builtin_amdgcn_s_setprio(1);
#pragma unroll
        for (int m = 0; m < 4; m++)
#pragma unroll
            for (int n = 0; n < 4; n++)
                acc[m][n] = __builtin_amdgcn_mfma_f32_16x16x32_bf16(ag[m], bg[n], acc[m][n], 0, 0, 0);
        __builtin_amdgcn_s_setprio(0);
    }

    // ---- epilogue ----  C mapping: col = lane&15, row = (lane>>4)*4 + reg
    const int r0 = (lane >> 4) * 4;
    const int cc = lane & 15;

    if constexpr (MODE == 0 || MODE == 2) {
#pragma unroll
        for (int i = 0; i < 4; i++)
#pragma unroll
            for (int j = 0; j < 4; j++)
#pragma unroll
                for (int v = 0; v < 4; v++) {
                    int row = wr * 64 + i * 16 + r0 + v;
                    int col = wc * 64 + j * 16 + cc;
                    float val = acc[i][j][v];
                    float r = fmaxf(val, 0.f);
                    val = r * r;
                    if constexpr (MODE == 0)
                        Hout[((size_t)e * CAPE + m0 + row) * NH + (n0 + col)] = f2bf(val);
                    else
                        Hout[(size_t)(m0 + row) * NHS + (n0 + col)] = f2bf(val);
                }
    } else if constexpr (MODE == 3) {
#pragma unroll
        for (int i = 0; i < 4; i++)
#pragma unroll
            for (int j = 0; j < 4; j++)
#pragma unroll
                for (int v = 0; v < 4; v++) {
                    int row = wr * 64 + i * 16 + r0 + v;
                    int col = wc * 64 + j * 16 + cc;
                    out[(size_t)(m0 + row) * ND + (n0 + col)] = acc[i][j][v];
                }
    } else {  // MODE 1: bf16 store to Ybuf, valid rows only
#pragma unroll
        for (int i = 0; i < 4; i++)
#pragma unroll
            for (int v = 0; v < 4; v++) {
                int row = wr * 64 + i * 16 + r0 + v;
                int grow = m0 + row;
                if (grow < mcnt) {
#pragma unroll
                    for (int j = 0; j < 4; j++) {
                        int col = wc * 64 + j * 16 + cc;
                        Hout[((size_t)e * CAPE + grow) * ND + (n0 + col)] = f2bf(acc[i][j][v]);
                    }
                }
            }
    }
}

// ---------------------------------------------------------------------------
extern "C" void kernel_launch(void* const* d_in, const int* in_sizes, int n_in,
                              void* d_out, int out_size, void* d_ws, size_t ws_size,
                              hipStream_t stream) {
    const float* X    = (const float*)d_in[0];
    const float* Gw   = (const float*)d_in[1];
    const float* bias = (const float*)d_in[2];
    const float* up_w = (const float*)d_in[3];
    const float* dn_w = (const float*)d_in[4];
    const float* sup  = (const float*)d_in[5];
    const float* sdn  = (const float*)d_in[6];
    float* out = (float*)d_out;

    char* ws = (char*)d_ws;
    size_t off = 0;
    auto alloc = [&](size_t bytes) -> void* {
        off = (off + 255) & ~(size_t)255;
        void* p = ws + off;
        off += bytes;
        return p;
    };
    int*   cnt      = (int*)  alloc(NE * 4);
    int*   topk_idx = (int*)  alloc((size_t)NT * NK * 4);
    float* topk_w   = (float*)alloc((size_t)NT * NK * 4);
    int*   pos_list = (int*)  alloc((size_t)NT * NK * 4);
    int*   tok_list = (int*)  alloc((size_t)NE * CAPE * 4);
    short* Hbuf     = (short*)alloc((size_t)NE * CAPE * NH * 2);   // 64 MB
    short* Sbuf     = (short*)alloc((size_t)NT * NHS * 2);         // 32 MB
    short* Xbf      = (short*)alloc((size_t)NT * ND * 2);          // 16 MB
    short* up_bf    = (short*)alloc((size_t)NE * NH * ND * 2);     // 128 MB
    short* dn_bf    = (short*)alloc((size_t)NE * ND * NH * 2);     // 128 MB
    short* sup_bf   = (short*)alloc((size_t)NHS * ND * 2);         // 16 MB
    short* sdn_bf   = (short*)alloc((size_t)ND * NHS * 2);         // 16 MB
    // Ybuf (128 MB) aliases [Xbf .. up_bf] — both dead once MODE0+MODE2 ran.
    short* Ybuf     = Xbf;

    gate_kernel<<<dim3(NT / 4), dim3(256), 0, stream>>>(X, Gw, bias, topk_idx, topk_w);
    zero_cnt<<<dim3(1), dim3(64), 0, stream>>>(cnt);
    dispatch_kernel<<<dim3(NT * NK / 256), dim3(256), 0, stream>>>(
        topk_idx, cnt, tok_list, pos_list);

    // bulk f32 -> bf16 conversion
    cvt_f2bf<<<dim3(1024), dim3(256), 0, stream>>>(X,    Xbf,    NT * ND / 8);
    cvt_f2bf<<<dim3(2048), dim3(256), 0, stream>>>(up_w, up_bf,  NE * NH * ND / 8);
    cvt_f2bf<<<dim3(2048), dim3(256), 0, stream>>>(dn_w, dn_bf,  NE * ND * NH / 8);
    cvt_f2bf<<<dim3(1024), dim3(256), 0, stream>>>(sup,  sup_bf, NHS * ND / 8);
    cvt_f2bf<<<dim3(1024), dim3(256), 0, stream>>>(sdn,  sdn_bf, ND * NHS / 8);

    // routed up: X gathered -> Hbuf
    moe_gemm4<0><<<dim3(NH / 128, CAPE / 128, NE), dim3(256), 0, stream>>>(
        Xbf, up_bf, cnt, tok_list, Hbuf, nullptr);
    // shared up: X -> Sbuf
    moe_gemm4<2><<<dim3(NHS / 128, NT / 128, 1), dim3(256), 0, stream>>>(
        Xbf, sup_bf, nullptr, nullptr, Sbuf, nullptr);
    // shared down: Sbuf -> out (f32 write; MUST precede combine)
    moe_gemm4<3><<<dim3(ND / 128, NT / 128, 1), dim3(256), 0, stream>>>(
        Sbuf, sdn_bf, nullptr, nullptr, nullptr, out);
    // routed down: Hbuf -> Ybuf
    moe_gemm4<1><<<dim3(ND / 128, CAPE / 128, NE), dim3(256), 0, stream>>>(
        Hbuf, dn_bf, cnt, tok_list, Ybuf, nullptr);
    // combine: out += sum_k w_k * Ybuf[e_k, pos_k]
    combine_kernel<<<dim3(NT), dim3(256), 0, stream>>>(
        topk_idx, topk_w, pos_list, Ybuf, out);
}

// Round 10
// 644.988 us; speedup vs baseline: 1.2249x; 1.0519x over previous
//
#include <hip/hip_runtime.h>

#define NE 32
#define NG 8
#define NK 4
#define ND 2048
#define NH 1024
#define NHS 4096
#define CAPE 1024
#define NT 4096

typedef float f32x4 __attribute__((ext_vector_type(4)));
typedef short s16x8 __attribute__((ext_vector_type(8)));

__device__ __forceinline__ short f2bf(float f) {
    return __builtin_bit_cast(short, (__bf16)f);
}
__device__ __forceinline__ float bf2f(short h) {
    return __builtin_bit_cast(float, ((unsigned)(unsigned short)h) << 16);
}

__device__ __forceinline__ void gload_lds16(const void* g, void* l) {
    __builtin_amdgcn_global_load_lds(
        (const __attribute__((address_space(1))) void*)g,
        (__attribute__((address_space(3))) void*)l, 16, 0, 0);
}

// ---------------------------------------------------------------------------
// Kernel 1: gating. One wave per token. fp32 logits, sigmoid, grouped top-k.
// ---------------------------------------------------------------------------
__global__ __launch_bounds__(256) void gate_kernel(
    const float* __restrict__ X, const float* __restrict__ Gw,
    const float* __restrict__ bias,
    int* __restrict__ topk_idx, float* __restrict__ topk_w)
{
    const int lane = threadIdx.x & 63;
    const int t = blockIdx.x * 4 + (threadIdx.x >> 6);
    const float* x = X + (size_t)t * ND;

    float xr[32];
#pragma unroll
    for (int i = 0; i < 32; i++) xr[i] = x[lane + i * 64];

    float scores[32];
#pragma unroll
    for (int e = 0; e < 32; e++) {
        const float* w = Gw + (size_t)e * ND;
        float a = 0.f;
#pragma unroll
        for (int i = 0; i < 32; i++) a = fmaf(xr[i], w[lane + i * 64], a);
#pragma unroll
        for (int s = 32; s > 0; s >>= 1) a += __shfl_xor(a, s);
        scores[e] = 1.0f / (1.0f + expf(-a));
    }

    float sc_c[32];
#pragma unroll
    for (int e = 0; e < 32; e++) sc_c[e] = scores[e] + bias[e];

    float gs[8];
#pragma unroll
    for (int g = 0; g < 8; g++) {
        float a = sc_c[4 * g], b = sc_c[4 * g + 1], c = sc_c[4 * g + 2], d = sc_c[4 * g + 3];
        float hi1 = fmaxf(a, b), lo1 = fminf(a, b);
        float hi2 = fmaxf(c, d), lo2 = fminf(c, d);
        float m1 = fmaxf(hi1, hi2);
        float m2 = fmaxf(fminf(hi1, hi2), fmaxf(lo1, lo2));
        gs[g] = m1 + m2;
    }

    unsigned gsel = 0;
#pragma unroll
    for (int it = 0; it < 4; it++) {
        int best = -1; float bv = -1e30f;
#pragma unroll
        for (int g = 0; g < 8; g++) {
            bool avail = !((gsel >> g) & 1);
            if (avail && gs[g] > bv) { bv = gs[g]; best = g; }
        }
        gsel |= 1u << best;
    }

    unsigned esel = 0;
    int idxs[4]; float wts[4];
#pragma unroll
    for (int it = 0; it < 4; it++) {
        int best = -1; float bv = -1e30f, braw = 0.f;
#pragma unroll
        for (int e = 0; e < 32; e++) {
            float mv = ((gsel >> (e >> 2)) & 1) ? sc_c[e] : 0.0f;
            bool avail = !((esel >> e) & 1);
            if (avail && mv > bv) { bv = mv; best = e; braw = scores[e]; }
        }
        esel |= 1u << best;
        idxs[it] = best; wts[it] = braw;
    }

    float s = wts[0] + wts[1] + wts[2] + wts[3] + 1e-20f;
    if (lane == 0) {
#pragma unroll
        for (int k = 0; k < 4; k++) {
            topk_idx[t * 4 + k] = idxs[k];
            topk_w[t * 4 + k] = wts[k] / s * 2.5f;
        }
    }
}

// ---------------------------------------------------------------------------
__global__ void zero_cnt(int* cnt) {
    if (threadIdx.x < NE) cnt[threadIdx.x] = 0;
}

__global__ void dispatch_kernel(const int* __restrict__ topk_idx,
                                int* __restrict__ cnt,
                                int* __restrict__ tok_list,
                                int* __restrict__ pos_list)
{
    int i = blockIdx.x * 256 + threadIdx.x;
    int e = topk_idx[i];
    int t = i >> 2;
    int pos = atomicAdd(&cnt[e], 1);
    pos_list[i] = pos;
    if (pos < CAPE) {
        tok_list[e * CAPE + pos] = t;
    }
}

// ---------------------------------------------------------------------------
// f32 -> bf16 bulk conversion (only used for X now; weights stay f32)
// ---------------------------------------------------------------------------
__global__ __launch_bounds__(256) void cvt_f2bf(const float* __restrict__ in,
                                                short* __restrict__ out, int n8)
{
    int i = blockIdx.x * 256 + threadIdx.x;
    int stride = gridDim.x * 256;
    for (; i < n8; i += stride) {
        const f32x4* p = (const f32x4*)(in + (size_t)i * 8);
        f32x4 a = p[0], b = p[1];
        s16x8 h;
        h[0] = f2bf(a[0]); h[1] = f2bf(a[1]); h[2] = f2bf(a[2]); h[3] = f2bf(a[3]);
        h[4] = f2bf(b[0]); h[5] = f2bf(b[1]); h[6] = f2bf(b[2]); h[7] = f2bf(b[3]);
        *(s16x8*)(out + (size_t)i * 8) = h;
    }
}

// ---------------------------------------------------------------------------
// Combine: out[t] = shared_down[t] (already in out) + sum_k w_k * Ybuf[e_k,pos_k]
// ---------------------------------------------------------------------------
__global__ __launch_bounds__(256) void combine_kernel(
    const int* __restrict__ topk_idx, const float* __restrict__ topk_w,
    const int* __restrict__ pos_list,
    const short* __restrict__ Ybuf, float* __restrict__ out)
{
    const int t = blockIdx.x;
    const int d0 = threadIdx.x * 8;

    int e[NK], p[NK]; float w[NK];
#pragma unroll
    for (int k = 0; k < NK; k++) {
        e[k] = topk_idx[t * NK + k];
        p[k] = pos_list[t * NK + k];
        w[k] = topk_w[t * NK + k];
    }

    float* orow = out + (size_t)t * ND + d0;
    f32x4 o0 = *(f32x4*)(orow);
    f32x4 o1 = *(f32x4*)(orow + 4);

#pragma unroll
    for (int k = 0; k < NK; k++) {
        if (p[k] < CAPE) {
            s16x8 y = *(const s16x8*)(Ybuf + ((size_t)e[k] * CAPE + p[k]) * ND + d0);
            o0[0] = fmaf(w[k], bf2f(y[0]), o0[0]);
            o0[1] = fmaf(w[k], bf2f(y[1]), o0[1]);
            o0[2] = fmaf(w[k], bf2f(y[2]), o0[2]);
            o0[3] = fmaf(w[k], bf2f(y[3]), o0[3]);
            o1[0] = fmaf(w[k], bf2f(y[4]), o1[0]);
            o1[1] = fmaf(w[k], bf2f(y[5]), o1[1]);
            o1[2] = fmaf(w[k], bf2f(y[6]), o1[2]);
            o1[3] = fmaf(w[k], bf2f(y[7]), o1[3]);
        }
    }
    *(f32x4*)(orow) = o0;
    *(f32x4*)(orow + 4) = o1;
}

// ---------------------------------------------------------------------------
// 4-wave GEMM: 128x128 tile, BK=64, double-buffered LDS (64 KB -> 2 blk/CU).
// A (bf16): global_load_lds, pre-swizzled source (R6/R9 zero-conflict scheme).
// B (f32 weights, NO pre-convert pass): reg-staged f32x4 -> cvt -> swizzled
// ds_write_b64.  Counted vmcnt(12) retires exactly {A(t+1), B(t+2)-regs}
// (queue: [A(t+1)4, B(t+2)8, A(t+2)4, B(t+3)8] = 24).  B regs double-buffered
// with static parity via 2-tile-unrolled loop.
// MODE 0: routed up   (A = Xbf gathered,  B = up_w[e],  out = relu2 -> Hbuf)
// MODE 1: routed down (A = Hbuf[e],       B = dn_w[e],  out = Ybuf bf16)
// MODE 2: shared up   (A = Xbf,           B = sup,      out = relu2 -> Sbuf)
// MODE 3: shared down (A = Sbuf,          B = sdn,      out = f32 write)
// ---------------------------------------------------------------------------
template <int MODE>
__global__ __launch_bounds__(256, 2) void moe_gemm4(
    const short* __restrict__ Abase, const float* __restrict__ Bbase,
    const int* __restrict__ cnt, const int* __restrict__ tok_list,
    short* __restrict__ Hout, float* __restrict__ out)
{
    constexpr int K = (MODE == 0) ? ND : (MODE == 1) ? NH : (MODE == 2) ? ND : NHS;
    constexpr int NTILES = K / 64;   // 32, 16, 32, 64 — all even

    const int e = blockIdx.z;
    const int m0 = blockIdx.y * 128, n0 = blockIdx.x * 128;

    int mcnt = 0;
    if constexpr (MODE == 0 || MODE == 1) {
        mcnt = min(cnt[e], CAPE);
        if (m0 >= mcnt) return;
    }

    __shared__ short As[2][128 * 64];
    __shared__ short Bs[2][128 * 64];

    const int tid = threadIdx.x;
    const int lane = tid & 63;
    const int wave = tid >> 6;
    const int wr = wave >> 1, wc = wave & 1;     // 2x2 wave grid, 64x64 each

    const short* Ab = Abase;
    const float* Bb = Bbase;
    if constexpr (MODE == 0) Bb += (size_t)e * NH * ND;
    if constexpr (MODE == 1) { Ab += (size_t)e * CAPE * NH; Bb += (size_t)e * ND * NH; }

    // ---- A staging (gload_lds): op = 32 rows x 64 elems ----
    const int srow = tid >> 3;                  // 0..31 row within op
    const int pA = tid & 7;                     // phys 16B slot 0..7
    const int gcolA = (pA ^ (srow & 7)) * 8;    // inverse-swizzled global col
    const short* asrc[4];
    int dstA[4];
#pragma unroll
    for (int o = 0; o < 4; o++) {
        int r = o * 32 + srow;
        if constexpr (MODE == 0) {
            int gr = min(m0 + r, mcnt - 1);
            int tok = tok_list[e * CAPE + gr];
            asrc[o] = Abase + (size_t)tok * ND + gcolA;
        } else if constexpr (MODE == 1) {
            int gr = min(m0 + r, mcnt - 1);
            asrc[o] = Ab + (size_t)gr * NH + gcolA;
        } else if constexpr (MODE == 2) {
            asrc[o] = Abase + (size_t)(m0 + r) * ND + gcolA;
        } else {
            asrc[o] = Abase + (size_t)(m0 + r) * NHS + gcolA;
        }
        dstA[o] = o * 2048 + wave * 512;        // linear dest (thread -> tid*8)
    }

    // ---- B staging (f32 reg-stage): pass o = 16 rows; lane-col = float4 ----
    const int brow = tid >> 4;                  // 0..15 row within pass
    const int lc = tid & 15;                    // float4 index (k = lc*4)
    const float* bsrc[8];
    int bdst[8];
#pragma unroll
    for (int o = 0; o < 8; o++) {
        int r = o * 16 + brow;                  // tile n-row 0..127
        bsrc[o] = Bb + (size_t)(n0 + r) * K + lc * 4;   // linear global source
        int ks = lc >> 1;                       // logical 16B slot 0..7
        bdst[o] = r * 64 + ((ks ^ (r & 7)) * 8) + (lc & 1) * 4;  // swizzled dest
    }

    // A stage for tile tt -> As[tt&1]
    auto STAGE_A = [&](int tt, int par) {
        const int ko = (tt < NTILES ? tt : NTILES - 1) * 64;
        short* Ad = As[par];
#pragma unroll
        for (int o = 0; o < 4; o++) gload_lds16(asrc[o] + ko, Ad + dstA[o]);
    };
    // B global->regs for tile tt
    auto BLOAD = [&](int tt, f32x4* regs) {
        const int ko = (tt < NTILES ? tt : NTILES - 1) * 64;
#pragma unroll
        for (int o = 0; o < 8; o++) regs[o] = *(const f32x4*)(bsrc[o] + ko);
    };
    // B regs -> cvt -> swizzled LDS write into Bs[par]
    auto BWRITE = [&](const f32x4* regs, int par) {
        short* Bd = Bs[par];
#pragma unroll
        for (int o = 0; o < 8; o++) {
            short4 h;
            h.x = f2bf(regs[o][0]); h.y = f2bf(regs[o][1]);
            h.z = f2bf(regs[o][2]); h.w = f2bf(regs[o][3]);
            *(short4*)(Bd + bdst[o]) = h;
        }
    };

    // ---- fragment read offsets (kh=0; kh=1 = off ^ 32) ----
    const int r16 = lane & 15;
    const int physbase = ((lane >> 4) ^ (lane & 7)) * 8;
    int offA[4], offB[4];
#pragma unroll
    for (int m = 0; m < 4; m++)
        offA[m] = (wr * 64 + m * 16 + r16) * 64 + physbase;
#pragma unroll
    for (int n = 0; n < 4; n++)
        offB[n] = (wc * 64 + n * 16 + r16) * 64 + physbase;

    f32x4 acc[4][4] = {};
    f32x4 brE[8], brO[8];    // B reg double-buffer (even/odd tiles)

    // ---- prologue ----
    STAGE_A(0, 0); STAGE_A(1, 1);          // vm: A0(4), A1(4)
    BLOAD(0, brE); BLOAD(1, brO);          // vm: B0(8), B1(8)  queue=24
    asm volatile("s_waitcnt vmcnt(8)" ::: "memory");    // retire A0,A1,B0
    __builtin_amdgcn_sched_barrier(0);
    BWRITE(brE, 0);
    asm volatile("s_waitcnt vmcnt(0)" ::: "memory");    // retire B1
    __builtin_amdgcn_sched_barrier(0);
    BWRITE(brO, 1);
    BLOAD(2, brE);                          // queue = [B2(8)]
    asm volatile("s_waitcnt lgkmcnt(0)" ::: "memory");
    __builtin_amdgcn_sched_barrier(0);

    // ---- main loop: 2 tiles per iteration (static reg parity) ----
#define GEMM_ITER(T, PAR, CONSUME, FILL)                                        \
    {                                                                           \
        __builtin_amdgcn_s_barrier();                                           \
        __builtin_amdgcn_sched_barrier(0);                                      \
        const short* At = As[PAR];                                              \
        const short* Bt = Bs[PAR];                                              \
        s16x8 af[4], bf[4];                                                     \
        _Pragma("unroll")                                                       \
        for (int m = 0; m < 4; m++) af[m] = *(const s16x8*)(At + offA[m]);      \
        _Pragma("unroll")                                                       \
        for (int n = 0; n < 4; n++) bf[n] = *(const s16x8*)(Bt + offB[n]);      \
        asm volatile("s_waitcnt lgkmcnt(0)" ::: "memory");                      \
        __builtin_amdgcn_sched_barrier(0);                                      \
        __builtin_amdgcn_s_setprio(1);                                          \
        _Pragma("unroll")                                                       \
        for (int m = 0; m < 4; m++)                                             \
            _Pragma("unroll")                                                   \
            for (int n = 0; n < 4; n++)                                         \
                acc[m][n] = __builtin_amdgcn_mfma_f32_16x16x32_bf16(            \
                    af[m], bf[n], acc[m][n], 0, 0, 0);                          \
        __builtin_amdgcn_s_setprio(0);                                          \
        s16x8 ag[4], bg[4];                                                     \
        _Pragma("unroll")                                                       \
        for (int m = 0; m < 4; m++) ag[m] = *(const s16x8*)(At + (offA[m] ^ 32)); \
        _Pragma("unroll")                                                       \
        for (int n = 0; n < 4; n++) bg[n] = *(const s16x8*)(Bt + (offB[n] ^ 32)); \
        asm volatile("s_waitcnt lgkmcnt(0)" ::: "memory");                      \
        __builtin_amdgcn_sched_barrier(0);                                      \
        __builtin_amdgcn_s_barrier();  /* all waves done with buf[PAR] */       \
        __builtin_amdgcn_sched_barrier(0);                                      \
        STAGE_A((T) + 2, PAR);                                                  \
        BLOAD((T) + 3, FILL);                                                   \
        asm volatile("s_waitcnt vmcnt(12)" ::: "memory"); /* A(t+1),B(t+2) in */ \
        __builtin_amdgcn_sched_barrier(0);                                      \
        BWRITE(CONSUME, PAR);                                                   \
        __builtin_amdgcn_s_setprio(1);                                          \
        _Pragma("unroll")                                                       \
        for (int m = 0; m < 4; m++)                                             \
            _Pragma("unroll")                                                   \
            for (int n = 0; n < 4; n++)                                         \
                acc[m][n] = __builtin_amdgcn_mfma_f32_16x16x32_bf16(            \
                    ag[m], bg[n], acc[m][n], 0, 0, 0);                          \
        __builtin_amdgcn_s_setprio(0);                                          \
        asm volatile("s_waitcnt lgkmcnt(0)" ::: "memory");                      \
        __builtin_amdgcn_sched_barrier(0);                                      \
    }

    for (int t = 0; t < NTILES; t += 2) {
        GEMM_ITER(t,     0, brE, brO);
        GEMM_ITER(t + 1, 1, brO, brE);
    }
#undef GEMM_ITER

    // ---- epilogue ----  C mapping: col = lane&15, row = (lane>>4)*4 + reg
    const int r0 = (lane >> 4) * 4;
    const int cc = lane & 15;

    if constexpr (MODE == 0 || MODE == 2) {
#pragma unroll
        for (int i = 0; i < 4; i++)
#pragma unroll
            for (int j = 0; j < 4; j++)
#pragma unroll
                for (int v = 0; v < 4; v++) {
                    int row = wr * 64 + i * 16 + r0 + v;
                    int col = wc * 64 + j * 16 + cc;
                    float val = acc[i][j][v];
                    float r = fmaxf(val, 0.f);
                    val = r * r;
                    if constexpr (MODE == 0)
                        Hout[((size_t)e * CAPE + m0 + row) * NH + (n0 + col)] = f2bf(val);
                    else
                        Hout[(size_t)(m0 + row) * NHS + (n0 + col)] = f2bf(val);
                }
    } else if constexpr (MODE == 3) {
#pragma unroll
        for (int i = 0; i < 4; i++)
#pragma unroll
            for (int j = 0; j < 4; j++)
#pragma unroll
                for (int v = 0; v < 4; v++) {
                    int row = wr * 64 + i * 16 + r0 + v;
                    int col = wc * 64 + j * 16 + cc;
                    out[(size_t)(m0 + row) * ND + (n0 + col)] = acc[i][j][v];
                }
    } else {  // MODE 1: bf16 store to Ybuf, valid rows only
#pragma unroll
        for (int i = 0; i < 4; i++)
#pragma unroll
            for (int v = 0; v < 4; v++) {
                int row = wr * 64 + i * 16 + r0 + v;
                int grow = m0 + row;
                if (grow < mcnt) {
#pragma unroll
                    for (int j = 0; j < 4; j++) {
                        int col = wc * 64 + j * 16 + cc;
                        Hout[((size_t)e * CAPE + grow) * ND + (n0 + col)] = f2bf(acc[i][j][v]);
                    }
                }
            }
    }
}

// ---------------------------------------------------------------------------
extern "C" void kernel_launch(void* const* d_in, const int* in_sizes, int n_in,
                              void* d_out, int out_size, void* d_ws, size_t ws_size,
                              hipStream_t stream) {
    const float* X    = (const float*)d_in[0];
    const float* Gw   = (const float*)d_in[1];
    const float* bias = (const float*)d_in[2];
    const float* up_w = (const float*)d_in[3];
    const float* dn_w = (const float*)d_in[4];
    const float* sup  = (const float*)d_in[5];
    const float* sdn  = (const float*)d_in[6];
    float* out = (float*)d_out;

    char* ws = (char*)d_ws;
    size_t off = 0;
    auto alloc = [&](size_t bytes) -> void* {
        off = (off + 255) & ~(size_t)255;
        void* p = ws + off;
        off += bytes;
        return p;
    };
    int*   cnt      = (int*)  alloc(NE * 4);
    int*   topk_idx = (int*)  alloc((size_t)NT * NK * 4);
    float* topk_w   = (float*)alloc((size_t)NT * NK * 4);
    int*   pos_list = (int*)  alloc((size_t)NT * NK * 4);
    int*   tok_list = (int*)  alloc((size_t)NE * CAPE * 4);
    short* Hbuf     = (short*)alloc((size_t)NE * CAPE * NH * 2);   // 64 MB
    short* Sbuf     = (short*)alloc((size_t)NT * NHS * 2);         // 32 MB
    short* Xbf      = (short*)alloc((size_t)NT * ND * 2);          // 16 MB
    short* Ybuf     = (short*)alloc((size_t)NE * CAPE * ND * 2);   // 128 MB

    gate_kernel<<<dim3(NT / 4), dim3(256), 0, stream>>>(X, Gw, bias, topk_idx, topk_w);
    zero_cnt<<<dim3(1), dim3(64), 0, stream>>>(cnt);
    dispatch_kernel<<<dim3(NT * NK / 256), dim3(256), 0, stream>>>(
        topk_idx, cnt, tok_list, pos_list);

    // only X needs pre-conversion now (weights consumed as f32 in-GEMM)
    cvt_f2bf<<<dim3(1024), dim3(256), 0, stream>>>(X, Xbf, NT * ND / 8);

    // routed up: X gathered -> Hbuf
    moe_gemm4<0><<<dim3(NH / 128, CAPE / 128, NE), dim3(256), 0, stream>>>(
        Xbf, up_w, cnt, tok_list, Hbuf, nullptr);
    // shared up: X -> Sbuf
    moe_gemm4<2><<<dim3(NHS / 128, NT / 128, 1), dim3(256), 0, stream>>>(
        Xbf, sup, nullptr, nullptr, Sbuf, nullptr);
    // shared down: Sbuf -> out (f32 write; MUST precede combine)
    moe_gemm4<3><<<dim3(ND / 128, NT / 128, 1), dim3(256), 0, stream>>>(
        Sbuf, sdn, nullptr, nullptr, nullptr, out);
    // routed down: Hbuf -> Ybuf
    moe_gemm4<1><<<dim3(ND / 128, CAPE / 128, NE), dim3(256), 0, stream>>>(
        Hbuf, dn_w, cnt, tok_list, Ybuf, nullptr);
    // combine: out += sum_k w_k * Ybuf[e_k, pos_k]
    combine_kernel<<<dim3(NT), dim3(256), 0, stream>>>(
        topk_idx, topk_w, pos_list, Ybuf, out);
}